// Round 7
// baseline (449.263 us; speedup 1.0000x reference)
//
#include <hip/hip_runtime.h>
#include <math.h>

#define N_ATOMS   131072
#define FEAT      256
#define UNITS     256
#define NSTRUCT   4096
#define ZDIM      1024   // 4*UNITS
#define QDIM      512    // 2*UNITS
#define KLSTM     768    // QDIM + UNITS

typedef __attribute__((ext_vector_type(8))) __bf16 bf16x8;
typedef __attribute__((ext_vector_type(4))) float  f32x4;

__device__ __forceinline__ float sigm(float v) { return 1.0f / (1.0f + __expf(-v)); }

__device__ __forceinline__ unsigned short bf16_rne(float v) {
    unsigned int u = __float_as_uint(v);
    u += 0x7fffu + ((u >> 16) & 1u);
    return (unsigned short)(u >> 16);
}
__device__ __forceinline__ float bf16_f32(unsigned short b) {
    return __uint_as_float(((unsigned int)b) << 16);
}
__device__ __forceinline__ bf16x8 frag_ld(const unsigned short* p) {
    uint4 u = *(const uint4*)p;
    bf16x8 r; __builtin_memcpy(&r, &u, 16); return r;
}

// ---------------------------------------------------------------------------
// Segment offsets: offs[s] = lower_bound(segment_ids, s)
// ---------------------------------------------------------------------------
__global__ void seg_offs_kernel(const int* __restrict__ seg, int* __restrict__ offs) {
    int s = blockIdx.x * blockDim.x + threadIdx.x;
    if (s > NSTRUCT) return;
    int lo = 0, hi = N_ATOMS;
    while (lo < hi) {
        int mid = (lo + hi) >> 1;
        if (seg[mid] < s) lo = mid + 1; else hi = mid;
    }
    offs[s] = lo;
}

// ---------------------------------------------------------------------------
// Weight prep: transpose + split f32 -> (hi, lo) bf16.  B^T layout [N][K].
// ---------------------------------------------------------------------------
__global__ __launch_bounds__(256) void prep_wd_kernel(
    const float* __restrict__ Wd, unsigned short* __restrict__ Th,
    unsigned short* __restrict__ Tl)
{
    int t = blockIdx.x * 256 + threadIdx.x;       // 65536 = 256*256
    int k = t >> 8, n = t & 255;
    float v = Wd[t];                              // Wd[k][n]
    unsigned short h = bf16_rne(v);
    unsigned short l = bf16_rne(v - bf16_f32(h));
    Th[n * FEAT + k] = h;
    Tl[n * FEAT + k] = l;
}

__global__ __launch_bounds__(256) void prep_wlstm_kernel(
    const float* __restrict__ Wk, const float* __restrict__ Wr,
    unsigned short* __restrict__ Th, unsigned short* __restrict__ Tl)
{
    int t = blockIdx.x * 256 + threadIdx.x;       // 786432 = 768*1024
    int k = t >> 10, n = t & 1023;
    float v = (k < QDIM) ? Wk[t] : Wr[t - QDIM * ZDIM];
    unsigned short h = bf16_rne(v);
    unsigned short l = bf16_rne(v - bf16_f32(h));
    Th[n * KLSTM + k] = h;
    Tl[n * KLSTM + k] = l;
}

// ---------------------------------------------------------------------------
// x = field @ Wd + bd   via split-bf16 MFMA (hh + lh + hl), BM=128, BN=256
// (full width), BK=32, 4 waves (2m x 2n), per-wave 64x128 = acc[4][8].
// A staged f32->hi/lo in-flight (once per m-block); B^T pre-split bf16.
// LDS rows padded to 40 shorts (80 B) -> frag reads ~2-way banked (free).
// ---------------------------------------------------------------------------
#define LDP 40
__global__ __launch_bounds__(256) void gemm_x_mfma(
    const float* __restrict__ A,                  // [131072][256] f32
    const unsigned short* __restrict__ BTh,       // [256][256] bf16 bits
    const unsigned short* __restrict__ BTl,
    const float* __restrict__ bias, float* __restrict__ C)
{
    __shared__ unsigned short Ah[128][LDP], Al[128][LDP];
    __shared__ unsigned short Bh[256][LDP], Bl[256][LDP];
    const int bm = blockIdx.x * 128;
    const int t  = threadIdx.x;
    const int w  = t >> 6, l = t & 63;
    const int wr = w & 1, wc = w >> 1;            // 2x2 waves
    const int lm = l & 15, koff = (l >> 4) * 8;

    f32x4 acc[4][8] = {};

    for (int k0 = 0; k0 < FEAT; k0 += 32) {
        #pragma unroll
        for (int i = 0; i < 4; ++i) {             // A: 128x32 f32 -> hi/lo
            int flat = t + i * 256;
            int m = flat >> 3, kq = flat & 7;
            const float4 v = *(const float4*)&A[(size_t)(bm + m) * FEAT + k0 + kq * 4];
            unsigned short h0 = bf16_rne(v.x), h1 = bf16_rne(v.y);
            unsigned short h2 = bf16_rne(v.z), h3 = bf16_rne(v.w);
            unsigned short l0 = bf16_rne(v.x - bf16_f32(h0));
            unsigned short l1 = bf16_rne(v.y - bf16_f32(h1));
            unsigned short l2 = bf16_rne(v.z - bf16_f32(h2));
            unsigned short l3 = bf16_rne(v.w - bf16_f32(h3));
            uint2 hw, lw;
            hw.x = (unsigned)h0 | ((unsigned)h1 << 16);
            hw.y = (unsigned)h2 | ((unsigned)h3 << 16);
            lw.x = (unsigned)l0 | ((unsigned)l1 << 16);
            lw.y = (unsigned)l2 | ((unsigned)l3 << 16);
            *(uint2*)&Ah[m][kq * 4] = hw;
            *(uint2*)&Al[m][kq * 4] = lw;
        }
        #pragma unroll
        for (int i = 0; i < 4; ++i) {             // B: 256 rows x 32 shorts (x2)
            int flat = t + i * 256;               // [0,1024)
            int n = flat >> 2, kc = flat & 3;
            *(uint4*)&Bh[n][kc * 8] = *(const uint4*)&BTh[(size_t)n * FEAT + k0 + kc * 8];
            *(uint4*)&Bl[n][kc * 8] = *(const uint4*)&BTl[(size_t)n * FEAT + k0 + kc * 8];
        }
        __syncthreads();
        bf16x8 ah[4], al[4];
        #pragma unroll
        for (int i = 0; i < 4; ++i) {
            ah[i] = frag_ld(&Ah[wr * 64 + i * 16 + lm][koff]);
            al[i] = frag_ld(&Al[wr * 64 + i * 16 + lm][koff]);
        }
        #pragma unroll
        for (int j = 0; j < 8; ++j) {
            bf16x8 bh = frag_ld(&Bh[wc * 128 + j * 16 + lm][koff]);
            bf16x8 bl = frag_ld(&Bl[wc * 128 + j * 16 + lm][koff]);
            #pragma unroll
            for (int i = 0; i < 4; ++i) {
                acc[i][j] = __builtin_amdgcn_mfma_f32_16x16x32_bf16(ah[i], bh, acc[i][j], 0, 0, 0);
                acc[i][j] = __builtin_amdgcn_mfma_f32_16x16x32_bf16(al[i], bh, acc[i][j], 0, 0, 0);
                acc[i][j] = __builtin_amdgcn_mfma_f32_16x16x32_bf16(ah[i], bl, acc[i][j], 0, 0, 0);
            }
        }
        __syncthreads();
    }

    const int lg4 = (l >> 4) * 4;
    #pragma unroll
    for (int i = 0; i < 4; ++i)
        #pragma unroll
        for (int j = 0; j < 8; ++j) {
            int col  = wc * 128 + j * 16 + lm;
            int row0 = bm + wr * 64 + i * 16 + lg4;
            float bb = bias[col];
            #pragma unroll
            for (int r = 0; r < 4; ++r)
                C[(size_t)(row0 + r) * FEAT + col] = acc[i][j][r] + bb;
        }
}

// ---------------------------------------------------------------------------
// z[4096,1024] = [qstar | h] @ [Wk;Wr] + b  via split-bf16 MFMA. K=768.
// (128x128 tile structure, validated round 5)
// ---------------------------------------------------------------------------
__global__ __launch_bounds__(256) void lstm_gemm_mfma(
    const float* __restrict__ qstar, const float* __restrict__ hsrc,
    const unsigned short* __restrict__ BTh,       // [1024][768]
    const unsigned short* __restrict__ BTl,
    const float* __restrict__ bias, float* __restrict__ z)
{
    __shared__ unsigned short Ah[128][LDP], Al[128][LDP];
    __shared__ unsigned short Bh[128][LDP], Bl[128][LDP];
    const int bn = blockIdx.x * 128;
    const int bm = blockIdx.y * 128;
    const int t  = threadIdx.x;
    const int w  = t >> 6, l = t & 63;
    const int wr = w & 1, wc = w >> 1;
    const int lm = l & 15, koff = (l >> 4) * 8;

    f32x4 acc[4][4] = {};

    for (int k0 = 0; k0 < KLSTM; k0 += 32) {
        const float* Asrc; int lda, kb;
        if (k0 < QDIM) { Asrc = qstar; lda = QDIM;  kb = k0; }
        else           { Asrc = hsrc;  lda = UNITS; kb = k0 - QDIM; }
        #pragma unroll
        for (int i = 0; i < 4; ++i) {
            int flat = t + i * 256;
            int m = flat >> 3, kq = flat & 7;
            const float4 v = *(const float4*)&Asrc[(size_t)(bm + m) * lda + kb + kq * 4];
            unsigned short h0 = bf16_rne(v.x), h1 = bf16_rne(v.y);
            unsigned short h2 = bf16_rne(v.z), h3 = bf16_rne(v.w);
            unsigned short l0 = bf16_rne(v.x - bf16_f32(h0));
            unsigned short l1 = bf16_rne(v.y - bf16_f32(h1));
            unsigned short l2 = bf16_rne(v.z - bf16_f32(h2));
            unsigned short l3 = bf16_rne(v.w - bf16_f32(h3));
            uint2 hw, lw;
            hw.x = (unsigned)h0 | ((unsigned)h1 << 16);
            hw.y = (unsigned)h2 | ((unsigned)h3 << 16);
            lw.x = (unsigned)l0 | ((unsigned)l1 << 16);
            lw.y = (unsigned)l2 | ((unsigned)l3 << 16);
            *(uint2*)&Ah[m][kq * 4] = hw;
            *(uint2*)&Al[m][kq * 4] = lw;
        }
        #pragma unroll
        for (int i = 0; i < 2; ++i) {
            int flat = t + i * 256;               // [0,512)
            int n = flat >> 2, kc = flat & 3;     // n in [0,128)
            *(uint4*)&Bh[n][kc * 8] = *(const uint4*)&BTh[(size_t)(bn + n) * KLSTM + k0 + kc * 8];
            *(uint4*)&Bl[n][kc * 8] = *(const uint4*)&BTl[(size_t)(bn + n) * KLSTM + k0 + kc * 8];
        }
        __syncthreads();
        bf16x8 ah[4], al[4];
        #pragma unroll
        for (int i = 0; i < 4; ++i) {
            ah[i] = frag_ld(&Ah[wr * 64 + i * 16 + lm][koff]);
            al[i] = frag_ld(&Al[wr * 64 + i * 16 + lm][koff]);
        }
        #pragma unroll
        for (int j = 0; j < 4; ++j) {
            bf16x8 bh = frag_ld(&Bh[wc * 64 + j * 16 + lm][koff]);
            bf16x8 bl = frag_ld(&Bl[wc * 64 + j * 16 + lm][koff]);
            #pragma unroll
            for (int i = 0; i < 4; ++i) {
                acc[i][j] = __builtin_amdgcn_mfma_f32_16x16x32_bf16(ah[i], bh, acc[i][j], 0, 0, 0);
                acc[i][j] = __builtin_amdgcn_mfma_f32_16x16x32_bf16(al[i], bh, acc[i][j], 0, 0, 0);
                acc[i][j] = __builtin_amdgcn_mfma_f32_16x16x32_bf16(ah[i], bl, acc[i][j], 0, 0, 0);
            }
        }
        __syncthreads();
    }

    const int lg4 = (l >> 4) * 4;
    #pragma unroll
    for (int i = 0; i < 4; ++i)
        #pragma unroll
        for (int j = 0; j < 4; ++j) {
            int col  = bn + wc * 64 + j * 16 + lm;
            int row0 = bm + wr * 64 + i * 16 + lg4;
            float bb = bias[col];
            #pragma unroll
            for (int r = 0; r < 4; ++r)
                z[(size_t)(row0 + r) * ZDIM + col] = acc[i][j][r] + bb;
        }
}

// ---------------------------------------------------------------------------
// Gates: h,c <- lstm gates(z, c).  Keras order i,f,g,o.
// ---------------------------------------------------------------------------
__global__ __launch_bounds__(256) void gates_kernel(
    const float* __restrict__ z, const float* __restrict__ c_in,
    float* __restrict__ h_out, float* __restrict__ c_out)
{
    int idx = blockIdx.x * 256 + threadIdx.x;
    int s = idx >> 8, ch = idx & 255;
    const float* zr = z + (size_t)s * ZDIM;
    float zi = zr[ch], zf = zr[256 + ch], zg = zr[512 + ch], zo = zr[768 + ch];
    float cold = c_in[idx];
    float cn = sigm(zf) * cold + sigm(zi) * tanhf(zg);
    float hn = sigm(zo) * tanhf(cn);
    h_out[idx] = hn;
    c_out[idx] = cn;
}

// Step-1 closed form: q*=0, h=0, c=0 -> z = b (same for every structure)
__global__ void h1c1_kernel(const float* __restrict__ b, float* __restrict__ hc_rows) {
    int ch = threadIdx.x;
    float zi = b[ch], zg = b[512 + ch], zo = b[768 + ch];
    float cn = sigm(zi) * tanhf(zg);
    float hn = sigm(zo) * tanhf(cn);
    hc_rows[ch] = hn;
    hc_rows[256 + ch] = cn;
}

__global__ __launch_bounds__(256) void bcast_kernel(
    const float* __restrict__ hc_rows, float* __restrict__ h, float* __restrict__ c)
{
    int idx = blockIdx.x * 256 + threadIdx.x;
    int ch = idx & 255;
    h[idx] = hc_rows[ch];
    c[idx] = hc_rows[256 + ch];
}

// ---------------------------------------------------------------------------
// Attention: one block per segment, thread = channel, online softmax.
// 4-way unrolled: tree-max shortens the serial dependency chain 4x.
// ---------------------------------------------------------------------------
__global__ __launch_bounds__(256) void attn_kernel(
    const float* __restrict__ x, const float* __restrict__ h,
    const int* __restrict__ offs, float* __restrict__ qstar_out)
{
    const int s = blockIdx.x;
    const int ch = threadIdx.x;
    const float q = h[(size_t)s * UNITS + ch];
    const int a0 = offs[s], a1 = offs[s + 1];

    float m = -INFINITY, ssum = 0.0f, r = 0.0f;
    int a = a0;
    for (; a + 3 < a1; a += 4) {
        float x0 = x[(size_t)(a + 0) * FEAT + ch];
        float x1 = x[(size_t)(a + 1) * FEAT + ch];
        float x2 = x[(size_t)(a + 2) * FEAT + ch];
        float x3 = x[(size_t)(a + 3) * FEAT + ch];
        float e0 = x0 * q, e1 = x1 * q, e2 = x2 * q, e3 = x3 * q;
        float mn = fmaxf(fmaxf(fmaxf(e0, e1), fmaxf(e2, e3)), m);
        float sc = __expf(m - mn);
        float p0 = __expf(e0 - mn), p1 = __expf(e1 - mn);
        float p2 = __expf(e2 - mn), p3 = __expf(e3 - mn);
        ssum = ssum * sc + ((p0 + p1) + (p2 + p3));
        r    = r    * sc + ((p0 * x0 + p1 * x1) + (p2 * x2 + p3 * x3));
        m = mn;
    }
    for (; a < a1; ++a) {
        float xv = x[(size_t)a * FEAT + ch];
        float e = xv * q;
        float mn = fmaxf(m, e);
        float sc = __expf(m - mn);
        float p = __expf(e - mn);
        ssum = ssum * sc + p;
        r = r * sc + p * xv;
        m = mn;
    }
    float rt = (a1 > a0) ? (r / ssum) : 0.0f;
    qstar_out[(size_t)s * QDIM + ch] = q;
    qstar_out[(size_t)s * QDIM + UNITS + ch] = rt;
}

// ---------------------------------------------------------------------------
extern "C" void kernel_launch(void* const* d_in, const int* in_sizes, int n_in,
                              void* d_out, int out_size, void* d_ws, size_t ws_size,
                              hipStream_t stream) {
    const float* field  = (const float*)d_in[0];
    const float* Wd     = (const float*)d_in[1];
    const float* bd     = (const float*)d_in[2];
    const float* Wk     = (const float*)d_in[3];
    const float* Wr     = (const float*)d_in[4];
    const float* b_lstm = (const float*)d_in[5];
    const int*   segids = (const int*)d_in[6];

    float* ws   = (float*)d_ws;
    float* x    = ws;                              // 33554432 f
    float* z    = x + (size_t)N_ATOMS * FEAT;      // 4194304 f
    float* qst  = z + (size_t)NSTRUCT * ZDIM;      // 2097152 f
    float* h    = qst + (size_t)NSTRUCT * QDIM;    // 1048576 f
    float* c    = h + (size_t)NSTRUCT * UNITS;     // 1048576 f
    float* hcr  = c + (size_t)NSTRUCT * UNITS;     // 512 f
    int*   offs = (int*)(hcr + 512);               // 4097 i

    // Pre-split weights live in the DEAD region of d_out (8 MB; we use 3.25 MB).
    // d_out is only written by the FINAL attn dispatch, after all weight reads.
    unsigned short* wdt_h = (unsigned short*)d_out;        // [256][256]
    unsigned short* wdt_l = wdt_h + 256 * 256;
    unsigned short* wt_h  = wdt_l + 256 * 256;             // [1024][768]
    unsigned short* wt_l  = wt_h + 1024 * 768;

    seg_offs_kernel<<<(NSTRUCT + 1 + 255) / 256, 256, 0, stream>>>(segids, offs);
    prep_wd_kernel<<<256, 256, 0, stream>>>(Wd, wdt_h, wdt_l);
    prep_wlstm_kernel<<<3072, 256, 0, stream>>>(Wk, Wr, wt_h, wt_l);

    // x = field @ Wd + bd   (full-width blocks: A converted exactly once)
    gemm_x_mfma<<<N_ATOMS / 128, 256, 0, stream>>>(field, wdt_h, wdt_l, bd, x);

    // step 1 (closed form LSTM from zero state)
    h1c1_kernel<<<1, 256, 0, stream>>>(b_lstm, hcr);
    bcast_kernel<<<NSTRUCT, 256, 0, stream>>>(hcr, h, c);
    attn_kernel<<<NSTRUCT, 256, 0, stream>>>(x, h, offs, qst);

    // steps 2, 3
    for (int step = 1; step < 3; ++step) {
        lstm_gemm_mfma<<<dim3(ZDIM / 128, NSTRUCT / 128), 256, 0, stream>>>(
            qst, h, wt_h, wt_l, b_lstm, z);
        gates_kernel<<<NSTRUCT, 256, 0, stream>>>(z, c, h, c);
        float* qdst = (step == 2) ? (float*)d_out : qst;
        attn_kernel<<<NSTRUCT, 256, 0, stream>>>(x, h, offs, qdst);
    }
}

// Round 9
// 447.510 us; speedup vs baseline: 1.0039x; 1.0039x over previous
//
#include <hip/hip_runtime.h>
#include <math.h>

#define N_ATOMS   131072
#define FEAT      256
#define UNITS     256
#define NSTRUCT   4096
#define ZDIM      1024   // 4*UNITS
#define QDIM      512    // 2*UNITS
#define KLSTM     768    // QDIM + UNITS
#define LDP       40     // LDS row pitch in shorts (80 B): frag reads 2-way banked

typedef __attribute__((ext_vector_type(8))) __bf16 bf16x8;
typedef __attribute__((ext_vector_type(4))) float  f32x4;

__device__ __forceinline__ float sigm(float v) { return 1.0f / (1.0f + __expf(-v)); }

__device__ __forceinline__ unsigned short bf16_rne(float v) {
    unsigned int u = __float_as_uint(v);
    u += 0x7fffu + ((u >> 16) & 1u);
    return (unsigned short)(u >> 16);
}
__device__ __forceinline__ float bf16_f32(unsigned short b) {
    return __uint_as_float(((unsigned int)b) << 16);
}
__device__ __forceinline__ bf16x8 frag_ld(const unsigned short* p) {
    uint4 u = *(const uint4*)p;
    bf16x8 r; __builtin_memcpy(&r, &u, 16); return r;
}

// ---------------------------------------------------------------------------
// Segment offsets: offs[s] = lower_bound(segment_ids, s)
// ---------------------------------------------------------------------------
__global__ void seg_offs_kernel(const int* __restrict__ seg, int* __restrict__ offs) {
    int s = blockIdx.x * blockDim.x + threadIdx.x;
    if (s > NSTRUCT) return;
    int lo = 0, hi = N_ATOMS;
    while (lo < hi) {
        int mid = (lo + hi) >> 1;
        if (seg[mid] < s) lo = mid + 1; else hi = mid;
    }
    offs[s] = lo;
}

// ---------------------------------------------------------------------------
// Weight prep: transpose + split f32 -> (hi, lo) bf16.  B^T layout [N][K].
// ---------------------------------------------------------------------------
__global__ __launch_bounds__(256) void prep_wd_kernel(
    const float* __restrict__ Wd, unsigned short* __restrict__ Th,
    unsigned short* __restrict__ Tl)
{
    int t = blockIdx.x * 256 + threadIdx.x;       // 65536 = 256*256
    int k = t >> 8, n = t & 255;
    float v = Wd[t];                              // Wd[k][n]
    unsigned short h = bf16_rne(v);
    unsigned short l = bf16_rne(v - bf16_f32(h));
    Th[n * FEAT + k] = h;
    Tl[n * FEAT + k] = l;
}

__global__ __launch_bounds__(256) void prep_wlstm_kernel(
    const float* __restrict__ Wk, const float* __restrict__ Wr,
    unsigned short* __restrict__ Th, unsigned short* __restrict__ Tl)
{
    int t = blockIdx.x * 256 + threadIdx.x;       // 786432 = 768*1024
    int k = t >> 10, n = t & 1023;
    float v = (k < QDIM) ? Wk[t] : Wr[t - QDIM * ZDIM];
    unsigned short h = bf16_rne(v);
    unsigned short l = bf16_rne(v - bf16_f32(h));
    Th[n * KLSTM + k] = h;
    Tl[n * KLSTM + k] = l;
}

// ---------------------------------------------------------------------------
// x = field @ Wd + bd  via split-bf16 MFMA (hh+lh+hl).
// Round-4 validated shape: BM=BN=128, BK=32, 4 waves (2x2), acc[4][4],
// ~92-110 VGPR, 40 KB LDS -> 4 blocks/CU.  Only change vs round 4: LDP=40.
// ---------------------------------------------------------------------------
__global__ __launch_bounds__(256) void gemm_x_mfma(
    const float* __restrict__ A,                  // [131072][256] f32
    const unsigned short* __restrict__ BTh,       // [256][256] bf16 bits
    const unsigned short* __restrict__ BTl,
    const float* __restrict__ bias, float* __restrict__ C)
{
    __shared__ unsigned short Ah[128][LDP], Al[128][LDP];
    __shared__ unsigned short Bh[128][LDP], Bl[128][LDP];
    const int bn = blockIdx.x * 128;
    const int bm = blockIdx.y * 128;
    const int t  = threadIdx.x;
    const int w  = t >> 6, l = t & 63;
    const int wr = w & 1, wc = w >> 1;
    const int lm = l & 15, koff = (l >> 4) * 8;

    f32x4 acc[4][4] = {};

    for (int k0 = 0; k0 < FEAT; k0 += 32) {
        #pragma unroll
        for (int i = 0; i < 2; ++i) {             // B first: pure copies
            int flat = t + i * 256;               // [0,512)
            int n = flat >> 2, kc = flat & 3;
            *(uint4*)&Bh[n][kc * 8] = *(const uint4*)&BTh[(size_t)(bn + n) * FEAT + k0 + kc * 8];
            *(uint4*)&Bl[n][kc * 8] = *(const uint4*)&BTl[(size_t)(bn + n) * FEAT + k0 + kc * 8];
        }
        #pragma unroll
        for (int i = 0; i < 4; ++i) {             // A: 128x32 f32 -> hi/lo
            int flat = t + i * 256;
            int m = flat >> 3, kq = flat & 7;
            const float4 v = *(const float4*)&A[(size_t)(bm + m) * FEAT + k0 + kq * 4];
            unsigned short h0 = bf16_rne(v.x), h1 = bf16_rne(v.y);
            unsigned short h2 = bf16_rne(v.z), h3 = bf16_rne(v.w);
            unsigned short l0 = bf16_rne(v.x - bf16_f32(h0));
            unsigned short l1 = bf16_rne(v.y - bf16_f32(h1));
            unsigned short l2 = bf16_rne(v.z - bf16_f32(h2));
            unsigned short l3 = bf16_rne(v.w - bf16_f32(h3));
            uint2 hw, lw;
            hw.x = (unsigned)h0 | ((unsigned)h1 << 16);
            hw.y = (unsigned)h2 | ((unsigned)h3 << 16);
            lw.x = (unsigned)l0 | ((unsigned)l1 << 16);
            lw.y = (unsigned)l2 | ((unsigned)l3 << 16);
            *(uint2*)&Ah[m][kq * 4] = hw;
            *(uint2*)&Al[m][kq * 4] = lw;
        }
        __syncthreads();
        bf16x8 ah[4], al[4];
        #pragma unroll
        for (int i = 0; i < 4; ++i) {
            ah[i] = frag_ld(&Ah[wr * 64 + i * 16 + lm][koff]);
            al[i] = frag_ld(&Al[wr * 64 + i * 16 + lm][koff]);
        }
        #pragma unroll
        for (int j = 0; j < 4; ++j) {
            bf16x8 bh = frag_ld(&Bh[wc * 64 + j * 16 + lm][koff]);
            bf16x8 bl = frag_ld(&Bl[wc * 64 + j * 16 + lm][koff]);
            #pragma unroll
            for (int i = 0; i < 4; ++i) {
                acc[i][j] = __builtin_amdgcn_mfma_f32_16x16x32_bf16(ah[i], bh, acc[i][j], 0, 0, 0);
                acc[i][j] = __builtin_amdgcn_mfma_f32_16x16x32_bf16(al[i], bh, acc[i][j], 0, 0, 0);
                acc[i][j] = __builtin_amdgcn_mfma_f32_16x16x32_bf16(ah[i], bl, acc[i][j], 0, 0, 0);
            }
        }
        __syncthreads();
    }

    const int lg4 = (l >> 4) * 4;
    #pragma unroll
    for (int i = 0; i < 4; ++i)
        #pragma unroll
        for (int j = 0; j < 4; ++j) {
            int col  = bn + wc * 64 + j * 16 + lm;
            int row0 = bm + wr * 64 + i * 16 + lg4;
            float bb = bias[col];
            #pragma unroll
            for (int r = 0; r < 4; ++r)
                C[(size_t)(row0 + r) * FEAT + col] = acc[i][j][r] + bb;
        }
}

// ---------------------------------------------------------------------------
// z[4096,1024] = [qstar | h] @ [Wk;Wr] + b  via split-bf16 MFMA. K=768.
// ---------------------------------------------------------------------------
__global__ __launch_bounds__(256) void lstm_gemm_mfma(
    const float* __restrict__ qstar, const float* __restrict__ hsrc,
    const unsigned short* __restrict__ BTh,       // [1024][768]
    const unsigned short* __restrict__ BTl,
    const float* __restrict__ bias, float* __restrict__ z)
{
    __shared__ unsigned short Ah[128][LDP], Al[128][LDP];
    __shared__ unsigned short Bh[128][LDP], Bl[128][LDP];
    const int bn = blockIdx.x * 128;
    const int bm = blockIdx.y * 128;
    const int t  = threadIdx.x;
    const int w  = t >> 6, l = t & 63;
    const int wr = w & 1, wc = w >> 1;
    const int lm = l & 15, koff = (l >> 4) * 8;

    f32x4 acc[4][4] = {};

    for (int k0 = 0; k0 < KLSTM; k0 += 32) {
        #pragma unroll
        for (int i = 0; i < 2; ++i) {             // B first
            int flat = t + i * 256;
            int n = flat >> 2, kc = flat & 3;
            *(uint4*)&Bh[n][kc * 8] = *(const uint4*)&BTh[(size_t)(bn + n) * KLSTM + k0 + kc * 8];
            *(uint4*)&Bl[n][kc * 8] = *(const uint4*)&BTl[(size_t)(bn + n) * KLSTM + k0 + kc * 8];
        }
        const float* Asrc; int lda, kb;
        if (k0 < QDIM) { Asrc = qstar; lda = QDIM;  kb = k0; }
        else           { Asrc = hsrc;  lda = UNITS; kb = k0 - QDIM; }
        #pragma unroll
        for (int i = 0; i < 4; ++i) {
            int flat = t + i * 256;
            int m = flat >> 3, kq = flat & 7;
            const float4 v = *(const float4*)&Asrc[(size_t)(bm + m) * lda + kb + kq * 4];
            unsigned short h0 = bf16_rne(v.x), h1 = bf16_rne(v.y);
            unsigned short h2 = bf16_rne(v.z), h3 = bf16_rne(v.w);
            unsigned short l0 = bf16_rne(v.x - bf16_f32(h0));
            unsigned short l1 = bf16_rne(v.y - bf16_f32(h1));
            unsigned short l2 = bf16_rne(v.z - bf16_f32(h2));
            unsigned short l3 = bf16_rne(v.w - bf16_f32(h3));
            uint2 hw, lw;
            hw.x = (unsigned)h0 | ((unsigned)h1 << 16);
            hw.y = (unsigned)h2 | ((unsigned)h3 << 16);
            lw.x = (unsigned)l0 | ((unsigned)l1 << 16);
            lw.y = (unsigned)l2 | ((unsigned)l3 << 16);
            *(uint2*)&Ah[m][kq * 4] = hw;
            *(uint2*)&Al[m][kq * 4] = lw;
        }
        __syncthreads();
        bf16x8 ah[4], al[4];
        #pragma unroll
        for (int i = 0; i < 4; ++i) {
            ah[i] = frag_ld(&Ah[wr * 64 + i * 16 + lm][koff]);
            al[i] = frag_ld(&Al[wr * 64 + i * 16 + lm][koff]);
        }
        #pragma unroll
        for (int j = 0; j < 4; ++j) {
            bf16x8 bh = frag_ld(&Bh[wc * 64 + j * 16 + lm][koff]);
            bf16x8 bl = frag_ld(&Bl[wc * 64 + j * 16 + lm][koff]);
            #pragma unroll
            for (int i = 0; i < 4; ++i) {
                acc[i][j] = __builtin_amdgcn_mfma_f32_16x16x32_bf16(ah[i], bh, acc[i][j], 0, 0, 0);
                acc[i][j] = __builtin_amdgcn_mfma_f32_16x16x32_bf16(al[i], bh, acc[i][j], 0, 0, 0);
                acc[i][j] = __builtin_amdgcn_mfma_f32_16x16x32_bf16(ah[i], bl, acc[i][j], 0, 0, 0);
            }
        }
        __syncthreads();
    }

    const int lg4 = (l >> 4) * 4;
    #pragma unroll
    for (int i = 0; i < 4; ++i)
        #pragma unroll
        for (int j = 0; j < 4; ++j) {
            int col  = bn + wc * 64 + j * 16 + lm;
            int row0 = bm + wr * 64 + i * 16 + lg4;
            float bb = bias[col];
            #pragma unroll
            for (int r = 0; r < 4; ++r)
                z[(size_t)(row0 + r) * ZDIM + col] = acc[i][j][r] + bb;
        }
}

// ---------------------------------------------------------------------------
// Gates: h,c <- lstm gates(z, c).  Keras order i,f,g,o.
// ---------------------------------------------------------------------------
__global__ __launch_bounds__(256) void gates_kernel(
    const float* __restrict__ z, const float* __restrict__ c_in,
    float* __restrict__ h_out, float* __restrict__ c_out)
{
    int idx = blockIdx.x * 256 + threadIdx.x;
    int s = idx >> 8, ch = idx & 255;
    const float* zr = z + (size_t)s * ZDIM;
    float zi = zr[ch], zf = zr[256 + ch], zg = zr[512 + ch], zo = zr[768 + ch];
    float cold = c_in[idx];
    float cn = sigm(zf) * cold + sigm(zi) * tanhf(zg);
    float hn = sigm(zo) * tanhf(cn);
    h_out[idx] = hn;
    c_out[idx] = cn;
}

// Step-1 closed form: q*=0, h=0, c=0 -> z = b (same for every structure)
__global__ void h1c1_kernel(const float* __restrict__ b, float* __restrict__ hc_rows) {
    int ch = threadIdx.x;
    float zi = b[ch], zg = b[512 + ch], zo = b[768 + ch];
    float cn = sigm(zi) * tanhf(zg);
    float hn = sigm(zo) * tanhf(cn);
    hc_rows[ch] = hn;
    hc_rows[256 + ch] = cn;
}

__global__ __launch_bounds__(256) void bcast_kernel(
    const float* __restrict__ hc_rows, float* __restrict__ h, float* __restrict__ c)
{
    int idx = blockIdx.x * 256 + threadIdx.x;
    int ch = idx & 255;
    h[idx] = hc_rows[ch];
    c[idx] = hc_rows[256 + ch];
}

// ---------------------------------------------------------------------------
// Attention: one block (1024 thr) per segment. thread=(ch, p): 4 partial
// online softmaxes over stride-4 atom subsets -> LDS merge. Serial
// dependency chain shortened 4x vs the 256-thread version.
// ---------------------------------------------------------------------------
__global__ __launch_bounds__(1024) void attn_kernel(
    const float* __restrict__ x, const float* __restrict__ h,
    const int* __restrict__ offs, float* __restrict__ qstar_out)
{
    __shared__ float Lm[4][UNITS], Ls[4][UNITS], Lr[4][UNITS];
    const int s  = blockIdx.x;
    const int t  = threadIdx.x;
    const int ch = t & 255;
    const int p  = t >> 8;                        // 0..3
    const float q = h[(size_t)s * UNITS + ch];
    const int a0 = offs[s], a1 = offs[s + 1];

    float m = -INFINITY, ssum = 0.0f, r = 0.0f;
    int a = a0 + p;
    for (; a + 12 < a1; a += 16) {                // 4-wide within the stride-4 subset
        float x0 = x[(size_t)(a +  0) * FEAT + ch];
        float x1 = x[(size_t)(a +  4) * FEAT + ch];
        float x2 = x[(size_t)(a +  8) * FEAT + ch];
        float x3 = x[(size_t)(a + 12) * FEAT + ch];
        float e0 = x0 * q, e1 = x1 * q, e2 = x2 * q, e3 = x3 * q;
        float mn = fmaxf(fmaxf(fmaxf(e0, e1), fmaxf(e2, e3)), m);
        float sc = __expf(m - mn);
        float p0 = __expf(e0 - mn), p1 = __expf(e1 - mn);
        float p2 = __expf(e2 - mn), p3 = __expf(e3 - mn);
        ssum = ssum * sc + ((p0 + p1) + (p2 + p3));
        r    = r    * sc + ((p0 * x0 + p1 * x1) + (p2 * x2 + p3 * x3));
        m = mn;
    }
    for (; a < a1; a += 4) {
        float xv = x[(size_t)a * FEAT + ch];
        float e = xv * q;
        float mn = fmaxf(m, e);
        float sc = __expf(m - mn);
        float pe = __expf(e - mn);
        ssum = ssum * sc + pe;
        r = r * sc + pe * xv;
        m = mn;
    }
    Lm[p][ch] = m; Ls[p][ch] = ssum; Lr[p][ch] = r;
    __syncthreads();

    if (p == 0) {
        float m0 = Lm[0][ch], m1 = Lm[1][ch], m2 = Lm[2][ch], m3 = Lm[3][ch];
        float ms = fmaxf(fmaxf(m0, m1), fmaxf(m2, m3));
        float rt = 0.0f;
        if (a1 > a0) {                            // ms finite here
            float w0 = __expf(m0 - ms), w1 = __expf(m1 - ms);
            float w2 = __expf(m2 - ms), w3 = __expf(m3 - ms);
            float S = Ls[0][ch] * w0 + Ls[1][ch] * w1 + Ls[2][ch] * w2 + Ls[3][ch] * w3;
            float R = Lr[0][ch] * w0 + Lr[1][ch] * w1 + Lr[2][ch] * w2 + Lr[3][ch] * w3;
            rt = R / S;
        }
        qstar_out[(size_t)s * QDIM + ch] = q;
        qstar_out[(size_t)s * QDIM + UNITS + ch] = rt;
    }
}

// ---------------------------------------------------------------------------
extern "C" void kernel_launch(void* const* d_in, const int* in_sizes, int n_in,
                              void* d_out, int out_size, void* d_ws, size_t ws_size,
                              hipStream_t stream) {
    const float* field  = (const float*)d_in[0];
    const float* Wd     = (const float*)d_in[1];
    const float* bd     = (const float*)d_in[2];
    const float* Wk     = (const float*)d_in[3];
    const float* Wr     = (const float*)d_in[4];
    const float* b_lstm = (const float*)d_in[5];
    const int*   segids = (const int*)d_in[6];

    float* ws   = (float*)d_ws;
    float* x    = ws;                              // 33554432 f
    float* z    = x + (size_t)N_ATOMS * FEAT;      // 4194304 f
    float* qst  = z + (size_t)NSTRUCT * ZDIM;      // 2097152 f
    float* h    = qst + (size_t)NSTRUCT * QDIM;    // 1048576 f
    float* c    = h + (size_t)NSTRUCT * UNITS;     // 1048576 f
    float* hcr  = c + (size_t)NSTRUCT * UNITS;     // 512 f
    int*   offs = (int*)(hcr + 512);               // 4097 i

    // Pre-split weights live in the DEAD region of d_out (8 MB; we use 3.25 MB).
    // d_out is only written by the FINAL attn dispatch, after all weight reads.
    unsigned short* wdt_h = (unsigned short*)d_out;        // [256][256]
    unsigned short* wdt_l = wdt_h + 256 * 256;
    unsigned short* wt_h  = wdt_l + 256 * 256;             // [1024][768]
    unsigned short* wt_l  = wt_h + 1024 * 768;

    seg_offs_kernel<<<(NSTRUCT + 1 + 255) / 256, 256, 0, stream>>>(segids, offs);
    prep_wd_kernel<<<256, 256, 0, stream>>>(Wd, wdt_h, wdt_l);
    prep_wlstm_kernel<<<3072, 256, 0, stream>>>(Wk, Wr, wt_h, wt_l);

    // x = field @ Wd + bd
    gemm_x_mfma<<<dim3(FEAT / 128, N_ATOMS / 128), 256, 0, stream>>>(
        field, wdt_h, wdt_l, bd, x);

    // step 1 (closed form LSTM from zero state)
    h1c1_kernel<<<1, 256, 0, stream>>>(b_lstm, hcr);
    bcast_kernel<<<NSTRUCT, 256, 0, stream>>>(hcr, h, c);
    attn_kernel<<<NSTRUCT, 1024, 0, stream>>>(x, h, offs, qst);

    // steps 2, 3
    for (int step = 1; step < 3; ++step) {
        lstm_gemm_mfma<<<dim3(ZDIM / 128, NSTRUCT / 128), 256, 0, stream>>>(
            qst, h, wt_h, wt_l, b_lstm, z);
        gates_kernel<<<NSTRUCT, 256, 0, stream>>>(z, c, h, c);
        float* qdst = (step == 2) ? (float*)d_out : qst;
        attn_kernel<<<NSTRUCT, 1024, 0, stream>>>(x, h, offs, qdst);
    }
}

// Round 10
// 413.651 us; speedup vs baseline: 1.0861x; 1.0819x over previous
//
#include <hip/hip_runtime.h>
#include <math.h>

#define N_ATOMS   131072
#define FEAT      256
#define UNITS     256
#define NSTRUCT   4096
#define ZDIM      1024   // 4*UNITS
#define QDIM      512    // 2*UNITS
#define KLSTM     512    // reduced: z = h*(Wk_top+Wr) + rt*Wk_bot  (qt == h)
#define LDP       40     // A-tile LDS pitch (shorts)

typedef __attribute__((ext_vector_type(8))) __bf16 bf16x8;
typedef __attribute__((ext_vector_type(4))) float  f32x4;

__device__ __forceinline__ float sigm(float v) { return 1.0f / (1.0f + __expf(-v)); }

__device__ __forceinline__ unsigned short bf16_rne(float v) {
    unsigned int u = __float_as_uint(v);
    u += 0x7fffu + ((u >> 16) & 1u);
    return (unsigned short)(u >> 16);
}
__device__ __forceinline__ float bf16_f32(unsigned short b) {
    return __uint_as_float(((unsigned int)b) << 16);
}
__device__ __forceinline__ bf16x8 frag_ld(const unsigned short* p) {
    uint4 u = *(const uint4*)p;
    bf16x8 r; __builtin_memcpy(&r, &u, 16); return r;
}
// async global->LDS, 16B per lane; LDS base must be wave-uniform (lane*16 auto)
__device__ __forceinline__ void gload16(const unsigned short* g, unsigned short* l) {
    __builtin_amdgcn_global_load_lds(
        (const __attribute__((address_space(1))) unsigned int*)g,
        (__attribute__((address_space(3))) unsigned int*)l, 16, 0, 0);
}

// ---------------------------------------------------------------------------
// Segment offsets: offs[s] = lower_bound(segment_ids, s)
// ---------------------------------------------------------------------------
__global__ void seg_offs_kernel(const int* __restrict__ seg, int* __restrict__ offs) {
    int s = blockIdx.x * blockDim.x + threadIdx.x;
    if (s > NSTRUCT) return;
    int lo = 0, hi = N_ATOMS;
    while (lo < hi) {
        int mid = (lo + hi) >> 1;
        if (seg[mid] < s) lo = mid + 1; else hi = mid;
    }
    offs[s] = lo;
}

// ---------------------------------------------------------------------------
// Weight prep: transpose + split f32 -> (hi, lo) bf16.  B^T layout [N][K].
// ---------------------------------------------------------------------------
__global__ __launch_bounds__(256) void prep_wd_kernel(
    const float* __restrict__ Wd, unsigned short* __restrict__ Th,
    unsigned short* __restrict__ Tl)
{
    int t = blockIdx.x * 256 + threadIdx.x;       // 65536 = 256*256
    int k = t >> 8, n = t & 255;
    float v = Wd[t];                              // Wd[k][n]
    unsigned short h = bf16_rne(v);
    unsigned short l = bf16_rne(v - bf16_f32(h));
    Th[n * FEAT + k] = h;
    Tl[n * FEAT + k] = l;
}

// Stacked LSTM weight [512][1024]: rows 0..255 = Wk_top + Wr, 256..511 = Wk_bot.
__global__ __launch_bounds__(256) void prep_wlstm_kernel(
    const float* __restrict__ Wk, const float* __restrict__ Wr,
    unsigned short* __restrict__ Th, unsigned short* __restrict__ Tl)
{
    int t = blockIdx.x * 256 + threadIdx.x;       // 524288 = 512*1024
    int k = t >> 10, n = t & 1023;
    float v = Wk[(size_t)k * ZDIM + n];
    if (k < 256) v += Wr[(size_t)k * ZDIM + n];
    unsigned short h = bf16_rne(v);
    unsigned short l = bf16_rne(v - bf16_f32(h));
    Th[(size_t)n * KLSTM + k] = h;
    Tl[(size_t)n * KLSTM + k] = l;
}

// ---------------------------------------------------------------------------
// Unified split-bf16 MFMA GEMM: C[M,N] = A_f32[M,K] @ BT[N,K]^T + bias.
// BM=BN=128, BK=32, 4 waves (2x2), acc[4][4].
// B: pre-split bf16 staged via global_load_lds (linear [128][32], no VGPR trip).
// A: f32 prefetched to regs one K-step ahead, converted hi/lo during stage.
// Per iter: convert A | barrier | loadA(k+1) issue, ds_read+MFMA | barrier |
//           issueB(k+1).  A-loads hide under MFMA; B-loads under next convert.
// ---------------------------------------------------------------------------
__global__ __launch_bounds__(256) void gemm_split(
    const float* __restrict__ A, int lda, int K,
    const unsigned short* __restrict__ BTh,       // [N][K] bf16 bits
    const unsigned short* __restrict__ BTl,
    const float* __restrict__ bias, float* __restrict__ C, int ldc)
{
    __shared__ unsigned short Ah[128][LDP], Al[128][LDP];
    __shared__ unsigned short Bh[128 * 32], Bl[128 * 32];
    const int bn = blockIdx.x * 128;
    const int bm = blockIdx.y * 128;
    const int t  = threadIdx.x;
    const int w  = t >> 6, l = t & 63;
    const int wr = w & 1, wc = w >> 1;
    const int lm = l & 15, koff = (l >> 4) * 8;

    f32x4 acc[4][4] = {};
    float4 pa[4];

    // ---- prologue: issue B(k0=0) + load A(k0=0) regs ----
    #pragma unroll
    for (int i = 0; i < 2; ++i) {
        int flat = t + i * 256;
        int n = flat >> 2, kc = flat & 3;
        gload16(&BTh[(size_t)(bn + n) * K + kc * 8], &Bh[(size_t)(w * 64 + i * 256) * 8]);
        gload16(&BTl[(size_t)(bn + n) * K + kc * 8], &Bl[(size_t)(w * 64 + i * 256) * 8]);
    }
    #pragma unroll
    for (int i = 0; i < 4; ++i) {
        int flat = t + i * 256;
        int m = flat >> 3, kq = flat & 7;
        pa[i] = *(const float4*)&A[(size_t)(bm + m) * lda + kq * 4];
    }

    for (int k0 = 0; k0 < K; k0 += 32) {
        // ---- convert current A regs -> LDS (hi/lo) ----
        #pragma unroll
        for (int i = 0; i < 4; ++i) {
            int flat = t + i * 256;
            int m = flat >> 3, kq = flat & 7;
            float4 v = pa[i];
            unsigned short h0 = bf16_rne(v.x), h1 = bf16_rne(v.y);
            unsigned short h2 = bf16_rne(v.z), h3 = bf16_rne(v.w);
            unsigned short l0 = bf16_rne(v.x - bf16_f32(h0));
            unsigned short l1 = bf16_rne(v.y - bf16_f32(h1));
            unsigned short l2 = bf16_rne(v.z - bf16_f32(h2));
            unsigned short l3 = bf16_rne(v.w - bf16_f32(h3));
            uint2 hw, lw;
            hw.x = (unsigned)h0 | ((unsigned)h1 << 16);
            hw.y = (unsigned)h2 | ((unsigned)h3 << 16);
            lw.x = (unsigned)l0 | ((unsigned)l1 << 16);
            lw.y = (unsigned)l2 | ((unsigned)l3 << 16);
            *(uint2*)&Ah[m][kq * 4] = hw;
            *(uint2*)&Al[m][kq * 4] = lw;
        }
        __syncthreads();                          // drains B gload + A writes

        const bool more = (k0 + 32) < K;
        if (more) {                               // A(k+1) -> regs; hides under MFMA
            #pragma unroll
            for (int i = 0; i < 4; ++i) {
                int flat = t + i * 256;
                int m = flat >> 3, kq = flat & 7;
                pa[i] = *(const float4*)&A[(size_t)(bm + m) * lda + k0 + 32 + kq * 4];
            }
        }

        bf16x8 ah[4], al[4];
        #pragma unroll
        for (int i = 0; i < 4; ++i) {
            ah[i] = frag_ld(&Ah[wr * 64 + i * 16 + lm][koff]);
            al[i] = frag_ld(&Al[wr * 64 + i * 16 + lm][koff]);
        }
        #pragma unroll
        for (int j = 0; j < 4; ++j) {
            bf16x8 bh = frag_ld(&Bh[(size_t)(wc * 64 + j * 16 + lm) * 32 + koff]);
            bf16x8 bl = frag_ld(&Bl[(size_t)(wc * 64 + j * 16 + lm) * 32 + koff]);
            #pragma unroll
            for (int i = 0; i < 4; ++i) {
                acc[i][j] = __builtin_amdgcn_mfma_f32_16x16x32_bf16(ah[i], bh, acc[i][j], 0, 0, 0);
                acc[i][j] = __builtin_amdgcn_mfma_f32_16x16x32_bf16(al[i], bh, acc[i][j], 0, 0, 0);
                acc[i][j] = __builtin_amdgcn_mfma_f32_16x16x32_bf16(ah[i], bl, acc[i][j], 0, 0, 0);
            }
        }
        __syncthreads();                          // B buffer free -> issue B(k+1)
        if (more) {
            #pragma unroll
            for (int i = 0; i < 2; ++i) {
                int flat = t + i * 256;
                int n = flat >> 2, kc = flat & 3;
                gload16(&BTh[(size_t)(bn + n) * K + k0 + 32 + kc * 8],
                        &Bh[(size_t)(w * 64 + i * 256) * 8]);
                gload16(&BTl[(size_t)(bn + n) * K + k0 + 32 + kc * 8],
                        &Bl[(size_t)(w * 64 + i * 256) * 8]);
            }
        }
    }

    const int lg4 = (l >> 4) * 4;
    #pragma unroll
    for (int i = 0; i < 4; ++i)
        #pragma unroll
        for (int j = 0; j < 4; ++j) {
            int col  = bn + wc * 64 + j * 16 + lm;
            int row0 = bm + wr * 64 + i * 16 + lg4;
            float bb = bias[col];
            #pragma unroll
            for (int r = 0; r < 4; ++r)
                C[(size_t)(row0 + r) * ldc + col] = acc[i][j][r] + bb;
        }
}

// ---------------------------------------------------------------------------
// Fused LSTM-gates + attention. One block (1024 thr) per structure.
// Phase 1 (threads 0-255): h,c from z (or b_lstm when use_z==0, c_old=0);
//   h kept in LDS as the query.  Phase 2: 4-partial online softmax over the
//   segment's atoms, LDS merge, write q_star=[h | rt] and c.
// ---------------------------------------------------------------------------
__global__ __launch_bounds__(1024) void attn_fused(
    const float* __restrict__ x, const float* __restrict__ zsrc, int use_z,
    float* __restrict__ c, const int* __restrict__ offs,
    float* __restrict__ qstar_out)
{
    __shared__ float hq[UNITS];
    __shared__ float Lm[4][UNITS], Ls[4][UNITS], Lr[4][UNITS];
    const int s  = blockIdx.x;
    const int t  = threadIdx.x;
    const int ch = t & 255;
    const int p  = t >> 8;                        // 0..3

    if (p == 0) {                                 // gates for this structure
        float zi, zf, zg, zo, cold;
        if (use_z) {
            const float* zr = zsrc + (size_t)s * ZDIM;
            zi = zr[ch]; zf = zr[256 + ch]; zg = zr[512 + ch]; zo = zr[768 + ch];
            cold = c[(size_t)s * UNITS + ch];
        } else {                                  // step 1: z = b, c_old = 0
            zi = zsrc[ch]; zf = zsrc[256 + ch]; zg = zsrc[512 + ch]; zo = zsrc[768 + ch];
            cold = 0.0f;
        }
        float cn = sigm(zf) * cold + sigm(zi) * tanhf(zg);
        float hn = sigm(zo) * tanhf(cn);
        c[(size_t)s * UNITS + ch] = cn;
        hq[ch] = hn;
    }
    __syncthreads();

    const float q = hq[ch];
    const int a0 = offs[s], a1 = offs[s + 1];

    float m = -INFINITY, ssum = 0.0f, r = 0.0f;
    int a = a0 + p;
    for (; a + 12 < a1; a += 16) {
        float x0 = x[(size_t)(a +  0) * FEAT + ch];
        float x1 = x[(size_t)(a +  4) * FEAT + ch];
        float x2 = x[(size_t)(a +  8) * FEAT + ch];
        float x3 = x[(size_t)(a + 12) * FEAT + ch];
        float e0 = x0 * q, e1 = x1 * q, e2 = x2 * q, e3 = x3 * q;
        float mn = fmaxf(fmaxf(fmaxf(e0, e1), fmaxf(e2, e3)), m);
        float sc = __expf(m - mn);
        float p0 = __expf(e0 - mn), p1 = __expf(e1 - mn);
        float p2 = __expf(e2 - mn), p3 = __expf(e3 - mn);
        ssum = ssum * sc + ((p0 + p1) + (p2 + p3));
        r    = r    * sc + ((p0 * x0 + p1 * x1) + (p2 * x2 + p3 * x3));
        m = mn;
    }
    for (; a < a1; a += 4) {
        float xv = x[(size_t)a * FEAT + ch];
        float e = xv * q;
        float mn = fmaxf(m, e);
        float sc = __expf(m - mn);
        float pe = __expf(e - mn);
        ssum = ssum * sc + pe;
        r = r * sc + pe * xv;
        m = mn;
    }
    Lm[p][ch] = m; Ls[p][ch] = ssum; Lr[p][ch] = r;
    __syncthreads();

    if (p == 0) {
        float m0 = Lm[0][ch], m1 = Lm[1][ch], m2 = Lm[2][ch], m3 = Lm[3][ch];
        float ms = fmaxf(fmaxf(m0, m1), fmaxf(m2, m3));
        float rt = 0.0f;
        if (a1 > a0) {
            float w0 = __expf(m0 - ms), w1 = __expf(m1 - ms);
            float w2 = __expf(m2 - ms), w3 = __expf(m3 - ms);
            float S = Ls[0][ch] * w0 + Ls[1][ch] * w1 + Ls[2][ch] * w2 + Ls[3][ch] * w3;
            float R = Lr[0][ch] * w0 + Lr[1][ch] * w1 + Lr[2][ch] * w2 + Lr[3][ch] * w3;
            rt = R / S;
        }
        qstar_out[(size_t)s * QDIM + ch] = q;
        qstar_out[(size_t)s * QDIM + UNITS + ch] = rt;
    }
}

// ---------------------------------------------------------------------------
extern "C" void kernel_launch(void* const* d_in, const int* in_sizes, int n_in,
                              void* d_out, int out_size, void* d_ws, size_t ws_size,
                              hipStream_t stream) {
    const float* field  = (const float*)d_in[0];
    const float* Wd     = (const float*)d_in[1];
    const float* bd     = (const float*)d_in[2];
    const float* Wk     = (const float*)d_in[3];
    const float* Wr     = (const float*)d_in[4];
    const float* b_lstm = (const float*)d_in[5];
    const int*   segids = (const int*)d_in[6];

    float* ws   = (float*)d_ws;
    float* x    = ws;                              // 33554432 f
    float* z    = x + (size_t)N_ATOMS * FEAT;      // 4194304 f
    float* qst  = z + (size_t)NSTRUCT * ZDIM;      // 2097152 f
    float* c    = qst + (size_t)NSTRUCT * QDIM;    // 1048576 f
    int*   offs = (int*)(c + (size_t)NSTRUCT * UNITS); // 4097 i

    // Pre-split weights in the DEAD region of d_out (8 MB; we use ~2.25 MB).
    // d_out is only written by the FINAL attn dispatch, after all weight reads.
    unsigned short* wdt_h = (unsigned short*)d_out;        // [256][256]
    unsigned short* wdt_l = wdt_h + 256 * 256;
    unsigned short* wt_h  = wdt_l + 256 * 256;             // [1024][512]
    unsigned short* wt_l  = wt_h + (size_t)ZDIM * KLSTM;

    seg_offs_kernel<<<(NSTRUCT + 1 + 255) / 256, 256, 0, stream>>>(segids, offs);
    prep_wd_kernel<<<256, 256, 0, stream>>>(Wd, wdt_h, wdt_l);
    prep_wlstm_kernel<<<ZDIM * KLSTM / 256, 256, 0, stream>>>(Wk, Wr, wt_h, wt_l);

    // x = field @ Wd + bd
    gemm_split<<<dim3(FEAT / 128, N_ATOMS / 128), 256, 0, stream>>>(
        field, FEAT, FEAT, wdt_h, wdt_l, bd, x, FEAT);

    // step 1: h,c from bias only (fused), then attention
    attn_fused<<<NSTRUCT, 1024, 0, stream>>>(x, b_lstm, 0, c, offs, qst);

    // steps 2, 3:  z = qst @ Wstacked + b  (K=512, qt==h algebraic cut)
    for (int step = 1; step < 3; ++step) {
        gemm_split<<<dim3(ZDIM / 128, NSTRUCT / 128), 256, 0, stream>>>(
            qst, KLSTM, KLSTM, wt_h, wt_l, b_lstm, z, ZDIM);
        float* qdst = (step == 2) ? (float*)d_out : qst;
        attn_fused<<<NSTRUCT, 1024, 0, stream>>>(x, z, 1, c, offs, qdst);
    }
}

// Round 12
// 407.835 us; speedup vs baseline: 1.1016x; 1.0143x over previous
//
#include <hip/hip_runtime.h>
#include <math.h>

#define N_ATOMS   131072
#define FEAT      256
#define UNITS     256
#define NSTRUCT   4096
#define ZDIM      1024   // 4*UNITS
#define QDIM      512    // 2*UNITS
#define KLSTM     512    // reduced: z = h*(Wk_top+Wr) + rt*Wk_bot  (qt == h)
#define LDP       40     // A-tile LDS pitch (shorts)

typedef __attribute__((ext_vector_type(8))) __bf16 bf16x8;
typedef __attribute__((ext_vector_type(4))) float  f32x4;

__device__ __forceinline__ float sigm(float v) { return 1.0f / (1.0f + __expf(-v)); }

__device__ __forceinline__ unsigned short bf16_rne(float v) {
    unsigned int u = __float_as_uint(v);
    u += 0x7fffu + ((u >> 16) & 1u);
    return (unsigned short)(u >> 16);
}
__device__ __forceinline__ float bf16_f32(unsigned short b) {
    return __uint_as_float(((unsigned int)b) << 16);
}
__device__ __forceinline__ bf16x8 frag_ld(const unsigned short* p) {
    uint4 u = *(const uint4*)p;
    bf16x8 r; __builtin_memcpy(&r, &u, 16); return r;
}
// async global->LDS, 16B per lane; LDS dest is wave-uniform base + lane*16
__device__ __forceinline__ void gload16(const unsigned short* g, unsigned short* l) {
    __builtin_amdgcn_global_load_lds(
        (const __attribute__((address_space(1))) unsigned int*)g,
        (__attribute__((address_space(3))) unsigned int*)l, 16, 0, 0);
}

// ---------------------------------------------------------------------------
// Segment offsets: offs[s] = lower_bound(segment_ids, s)
// ---------------------------------------------------------------------------
__global__ void seg_offs_kernel(const int* __restrict__ seg, int* __restrict__ offs) {
    int s = blockIdx.x * blockDim.x + threadIdx.x;
    if (s > NSTRUCT) return;
    int lo = 0, hi = N_ATOMS;
    while (lo < hi) {
        int mid = (lo + hi) >> 1;
        if (seg[mid] < s) lo = mid + 1; else hi = mid;
    }
    offs[s] = lo;
}

// ---------------------------------------------------------------------------
// Weight prep: transpose + split f32 -> (hi, lo) bf16.  B^T layout [N][K].
// ---------------------------------------------------------------------------
__global__ __launch_bounds__(256) void prep_wd_kernel(
    const float* __restrict__ Wd, unsigned short* __restrict__ Th,
    unsigned short* __restrict__ Tl)
{
    int t = blockIdx.x * 256 + threadIdx.x;       // 65536 = 256*256
    int k = t >> 8, n = t & 255;
    float v = Wd[t];                              // Wd[k][n]
    unsigned short h = bf16_rne(v);
    unsigned short l = bf16_rne(v - bf16_f32(h));
    Th[n * FEAT + k] = h;
    Tl[n * FEAT + k] = l;
}

// Stacked LSTM weight [512][1024]: rows 0..255 = Wk_top + Wr, 256..511 = Wk_bot.
__global__ __launch_bounds__(256) void prep_wlstm_kernel(
    const float* __restrict__ Wk, const float* __restrict__ Wr,
    unsigned short* __restrict__ Th, unsigned short* __restrict__ Tl)
{
    int t = blockIdx.x * 256 + threadIdx.x;       // 524288 = 512*1024
    int k = t >> 10, n = t & 1023;
    float v = Wk[(size_t)k * ZDIM + n];
    if (k < 256) v += Wr[(size_t)k * ZDIM + n];
    unsigned short h = bf16_rne(v);
    unsigned short l = bf16_rne(v - bf16_f32(h));
    Th[(size_t)n * KLSTM + k] = h;
    Tl[(size_t)n * KLSTM + k] = l;
}

// ---------------------------------------------------------------------------
// Unified split-bf16 MFMA GEMM: C[M,N] = A_f32[M,K] @ BT[N,K]^T + bias.
// BM=BN=128, BK=32, 4 waves (2x2), acc[4][4].  (validated round 10; unchanged)
// ---------------------------------------------------------------------------
__global__ __launch_bounds__(256) void gemm_split(
    const float* __restrict__ A, int lda, int K,
    const unsigned short* __restrict__ BTh,       // [N][K] bf16 bits
    const unsigned short* __restrict__ BTl,
    const float* __restrict__ bias, float* __restrict__ C, int ldc)
{
    __shared__ unsigned short Ah[128][LDP], Al[128][LDP];
    __shared__ unsigned short Bh[128 * 32], Bl[128 * 32];
    const int bn = blockIdx.x * 128;
    const int bm = blockIdx.y * 128;
    const int t  = threadIdx.x;
    const int w  = t >> 6, l = t & 63;
    const int wr = w & 1, wc = w >> 1;
    const int lm = l & 15, koff = (l >> 4) * 8;

    f32x4 acc[4][4] = {};
    float4 pa[4];

    #pragma unroll
    for (int i = 0; i < 2; ++i) {
        int flat = t + i * 256;
        int n = flat >> 2, kc = flat & 3;
        gload16(&BTh[(size_t)(bn + n) * K + kc * 8], &Bh[(size_t)(w * 64 + i * 256) * 8]);
        gload16(&BTl[(size_t)(bn + n) * K + kc * 8], &Bl[(size_t)(w * 64 + i * 256) * 8]);
    }
    #pragma unroll
    for (int i = 0; i < 4; ++i) {
        int flat = t + i * 256;
        int m = flat >> 3, kq = flat & 7;
        pa[i] = *(const float4*)&A[(size_t)(bm + m) * lda + kq * 4];
    }

    for (int k0 = 0; k0 < K; k0 += 32) {
        #pragma unroll
        for (int i = 0; i < 4; ++i) {
            int flat = t + i * 256;
            int m = flat >> 3, kq = flat & 7;
            float4 v = pa[i];
            unsigned short h0 = bf16_rne(v.x), h1 = bf16_rne(v.y);
            unsigned short h2 = bf16_rne(v.z), h3 = bf16_rne(v.w);
            unsigned short l0 = bf16_rne(v.x - bf16_f32(h0));
            unsigned short l1 = bf16_rne(v.y - bf16_f32(h1));
            unsigned short l2 = bf16_rne(v.z - bf16_f32(h2));
            unsigned short l3 = bf16_rne(v.w - bf16_f32(h3));
            uint2 hw, lw;
            hw.x = (unsigned)h0 | ((unsigned)h1 << 16);
            hw.y = (unsigned)h2 | ((unsigned)h3 << 16);
            lw.x = (unsigned)l0 | ((unsigned)l1 << 16);
            lw.y = (unsigned)l2 | ((unsigned)l3 << 16);
            *(uint2*)&Ah[m][kq * 4] = hw;
            *(uint2*)&Al[m][kq * 4] = lw;
        }
        __syncthreads();

        const bool more = (k0 + 32) < K;
        if (more) {
            #pragma unroll
            for (int i = 0; i < 4; ++i) {
                int flat = t + i * 256;
                int m = flat >> 3, kq = flat & 7;
                pa[i] = *(const float4*)&A[(size_t)(bm + m) * lda + k0 + 32 + kq * 4];
            }
        }

        bf16x8 ah[4], al[4];
        #pragma unroll
        for (int i = 0; i < 4; ++i) {
            ah[i] = frag_ld(&Ah[wr * 64 + i * 16 + lm][koff]);
            al[i] = frag_ld(&Al[wr * 64 + i * 16 + lm][koff]);
        }
        #pragma unroll
        for (int j = 0; j < 4; ++j) {
            bf16x8 bh = frag_ld(&Bh[(size_t)(wc * 64 + j * 16 + lm) * 32 + koff]);
            bf16x8 bl = frag_ld(&Bl[(size_t)(wc * 64 + j * 16 + lm) * 32 + koff]);
            #pragma unroll
            for (int i = 0; i < 4; ++i) {
                acc[i][j] = __builtin_amdgcn_mfma_f32_16x16x32_bf16(ah[i], bh, acc[i][j], 0, 0, 0);
                acc[i][j] = __builtin_amdgcn_mfma_f32_16x16x32_bf16(al[i], bh, acc[i][j], 0, 0, 0);
                acc[i][j] = __builtin_amdgcn_mfma_f32_16x16x32_bf16(ah[i], bl, acc[i][j], 0, 0, 0);
            }
        }
        __syncthreads();
        if (more) {
            #pragma unroll
            for (int i = 0; i < 2; ++i) {
                int flat = t + i * 256;
                int n = flat >> 2, kc = flat & 3;
                gload16(&BTh[(size_t)(bn + n) * K + k0 + 32 + kc * 8],
                        &Bh[(size_t)(w * 64 + i * 256) * 8]);
                gload16(&BTl[(size_t)(bn + n) * K + k0 + 32 + kc * 8],
                        &Bl[(size_t)(w * 64 + i * 256) * 8]);
            }
        }
    }

    const int lg4 = (l >> 4) * 4;
    #pragma unroll
    for (int i = 0; i < 4; ++i)
        #pragma unroll
        for (int j = 0; j < 4; ++j) {
            int col  = bn + wc * 64 + j * 16 + lm;
            int row0 = bm + wr * 64 + i * 16 + lg4;
            float bb = bias[col];
            #pragma unroll
            for (int r = 0; r < 4; ++r)
                C[(size_t)(row0 + r) * ldc + col] = acc[i][j][r] + bb;
        }
}

// ---------------------------------------------------------------------------
// Fused LSTM-gates + attention.  256 threads / block (one block per structure),
// NO LDS, NO barriers: thread ch computes its own gate channel (q = h[ch] stays
// in-register), then runs 8 INDEPENDENT online-softmax states over stride-8
// atoms (8-wide load ILP, 8x shorter serial exp/fmax chain), merged in-register.
// ---------------------------------------------------------------------------
__global__ __launch_bounds__(256) void attn_fused(
    const float* __restrict__ x, const float* __restrict__ zsrc, int use_z,
    float* __restrict__ c, const int* __restrict__ offs,
    float* __restrict__ qstar_out)
{
    const int s  = blockIdx.x;
    const int ch = threadIdx.x;

    // ---- gates (per-thread, no cross-thread dependency) ----
    float zi, zf, zg, zo, cold;
    if (use_z) {
        const float* zr = zsrc + (size_t)s * ZDIM;
        zi = zr[ch]; zf = zr[256 + ch]; zg = zr[512 + ch]; zo = zr[768 + ch];
        cold = c[(size_t)s * UNITS + ch];
    } else {                                      // step 1: z = b, c_old = 0
        zi = zsrc[ch]; zf = zsrc[256 + ch]; zg = zsrc[512 + ch]; zo = zsrc[768 + ch];
        cold = 0.0f;
    }
    float cn = sigm(zf) * cold + sigm(zi) * tanhf(zg);
    float q  = sigm(zo) * tanhf(cn);              // h == qt
    c[(size_t)s * UNITS + ch] = cn;

    // ---- 8-state online softmax over this segment's atoms ----
    const int a0 = offs[s], a1 = offs[s + 1];
    float m[8], ss[8], rr[8];
    #pragma unroll
    for (int j = 0; j < 8; ++j) { m[j] = -INFINITY; ss[j] = 0.0f; rr[j] = 0.0f; }

    int a = a0;
    for (; a + 7 < a1; a += 8) {
        float xv[8];
        #pragma unroll
        for (int j = 0; j < 8; ++j) xv[j] = x[(size_t)(a + j) * FEAT + ch];
        #pragma unroll
        for (int j = 0; j < 8; ++j) {
            float e  = xv[j] * q;
            float mn = fmaxf(m[j], e);
            float sc = __expf(m[j] - mn);
            float pe = __expf(e - mn);
            ss[j] = ss[j] * sc + pe;
            rr[j] = rr[j] * sc + pe * xv[j];
            m[j] = mn;
        }
    }
    for (; a < a1; ++a) {                         // tail -> state 0
        float xv = x[(size_t)a * FEAT + ch];
        float e  = xv * q;
        float mn = fmaxf(m[0], e);
        float sc = __expf(m[0] - mn);
        float pe = __expf(e - mn);
        ss[0] = ss[0] * sc + pe;
        rr[0] = rr[0] * sc + pe * xv;
        m[0] = mn;
    }

    float rt = 0.0f;
    if (a1 > a0) {
        float ms = m[0];
        #pragma unroll
        for (int j = 1; j < 8; ++j) ms = fmaxf(ms, m[j]);
        float S = 0.0f, R = 0.0f;
        #pragma unroll
        for (int j = 0; j < 8; ++j) {
            float wj = __expf(m[j] - ms);         // exp(-inf)=0 for unused states
            S += ss[j] * wj;
            R += rr[j] * wj;
        }
        rt = R / S;
    }
    qstar_out[(size_t)s * QDIM + ch] = q;
    qstar_out[(size_t)s * QDIM + UNITS + ch] = rt;
}

// ---------------------------------------------------------------------------
extern "C" void kernel_launch(void* const* d_in, const int* in_sizes, int n_in,
                              void* d_out, int out_size, void* d_ws, size_t ws_size,
                              hipStream_t stream) {
    const float* field  = (const float*)d_in[0];
    const float* Wd     = (const float*)d_in[1];
    const float* bd     = (const float*)d_in[2];
    const float* Wk     = (const float*)d_in[3];
    const float* Wr     = (const float*)d_in[4];
    const float* b_lstm = (const float*)d_in[5];
    const int*   segids = (const int*)d_in[6];

    float* ws   = (float*)d_ws;
    float* x    = ws;                              // 33554432 f
    float* z    = x + (size_t)N_ATOMS * FEAT;      // 4194304 f
    float* qst  = z + (size_t)NSTRUCT * ZDIM;      // 2097152 f
    float* c    = qst + (size_t)NSTRUCT * QDIM;    // 1048576 f
    int*   offs = (int*)(c + (size_t)NSTRUCT * UNITS); // 4097 i

    // Pre-split weights in the DEAD region of d_out (8 MB; we use ~2.25 MB).
    // d_out is only written by the FINAL attn dispatch, after all weight reads.
    unsigned short* wdt_h = (unsigned short*)d_out;        // [256][256]
    unsigned short* wdt_l = wdt_h + 256 * 256;
    unsigned short* wt_h  = wdt_l + 256 * 256;             // [1024][512]
    unsigned short* wt_l  = wt_h + (size_t)ZDIM * KLSTM;

    seg_offs_kernel<<<(NSTRUCT + 1 + 255) / 256, 256, 0, stream>>>(segids, offs);
    prep_wd_kernel<<<256, 256, 0, stream>>>(Wd, wdt_h, wdt_l);
    prep_wlstm_kernel<<<ZDIM * KLSTM / 256, 256, 0, stream>>>(Wk, Wr, wt_h, wt_l);

    // x = field @ Wd + bd
    gemm_split<<<dim3(FEAT / 128, N_ATOMS / 128), 256, 0, stream>>>(
        field, FEAT, FEAT, wdt_h, wdt_l, bd, x, FEAT);

    // step 1: h,c from bias only (fused), then attention
    attn_fused<<<NSTRUCT, 256, 0, stream>>>(x, b_lstm, 0, c, offs, qst);

    // steps 2, 3:  z = qst @ Wstacked + b  (K=512, qt==h algebraic cut)
    for (int step = 1; step < 3; ++step) {
        gemm_split<<<dim3(ZDIM / 128, NSTRUCT / 128), 256, 0, stream>>>(
            qst, KLSTM, KLSTM, wt_h, wt_l, b_lstm, z, ZDIM);
        float* qdst = (step == 2) ? (float*)d_out : qst;
        attn_fused<<<NSTRUCT, 256, 0, stream>>>(x, z, 1, c, offs, qdst);
    }
}